// Round 10
// baseline (67.958 us; speedup 1.0000x reference)
//
#include <hip/hip_runtime.h>
#include <math.h>

#define NB 16
#define NN 64
#define NF 64
#define NH 4
#define NR 50
#define NC 256

typedef __attribute__((ext_vector_type(8))) short short8;
typedef __attribute__((ext_vector_type(4))) float f32x4;

// ---- wpack short offsets ----
#define WS_WE1R 0          // 512 entries (K=64 rbf part of W_e1)
#define WS_WE2  4096       // 640 entries (512 We2 + 128 We2s head-replicated)
#define WS_WX   9216       // 8192 entries [ct(16)][h(4)][ks(2)][lane]
// ---- float offsets ----
#define MID_F   40960
#define E1_F    (MID_F + 131072)
#define BS2_F   (E1_F + 131072)

// ---- LDS f32 scratch offsets (aliased over s_A, free after P3) ----
#define SP_COMB 0      // 768: comb [k][256]
#define SP_HCP  768    // 256
#define SP_IN   1024   // 384: [h | hagg | hcomb]
#define SP_RED  1408   // 256: 4 x 64 partials
#define SP_VEC  1664   // 64
#define SP_HO   1728   // 64
#define SP_MISC 1792   // 4: gate, dv0, dv1, dv2

__device__ __forceinline__ float siluf(float x) { return x / (1.f + __expf(-x)); }
__device__ __forceinline__ float tanhfast(float x) { return 1.f - 2.f / (__expf(2.f * x) + 1.f); }

__device__ __forceinline__ short f2bfs(float f) {
    __bf16 b = (__bf16)f;
    union { __bf16 b; short s; } u; u.b = b; return u.s;
}
__device__ __forceinline__ float bf1(ushort u) {
    union { unsigned u; float f; } c; c.u = ((unsigned)u) << 16; return c.f;
}
__device__ __forceinline__ float bflo(unsigned u) {
    union { unsigned u; float f; } c; c.u = u << 16; return c.f;
}
__device__ __forceinline__ float bfhi(unsigned u) {
    union { unsigned u; float f; } c; c.u = u & 0xFFFF0000u; return c.f;
}
__device__ __forceinline__ float wave_sum(float v) {
#pragma unroll
    for (int s = 32; s >= 1; s >>= 1) v += __shfl_xor(v, s);
    return v;
}

// =============== prep: weight packs + bs2 + per-node precomputes (wave-per-node) ===============
__global__ __launch_bounds__(256)
void prep_kernel(const float* __restrict__ W_e1, const float* __restrict__ b_e1,
                 const float* __restrict__ W_e2, const float* __restrict__ b_e2,
                 const float* __restrict__ W_sem, const float* __restrict__ b_sem,
                 const float* __restrict__ W_xmix,
                 const float* __restrict__ h, const float* __restrict__ W_in,
                 const float* __restrict__ b_in,
                 short* __restrict__ wpack, float* __restrict__ mid,
                 float* __restrict__ e1, float* __restrict__ bs2)
{
    int blk = blockIdx.x, t = threadIdx.x;
    if (blk < 37) {
        int s = blk * 256 + t;
        if (s >= 9344) return;
        short8 val;
        if (s < 512) {               // W_e1 rbf part K=64
            int cl = s & 15, g = (s >> 4) & 3, q = s >> 6;
            int ks = q & 1, nt = q >> 1;
            int c = nt * 16 + cl, k0 = 32 * ks + 8 * g;
#pragma unroll
            for (int i = 0; i < 8; i++) {
                int kr = k0 + i;
                float f = (kr < 50) ? W_e1[(128 + kr) * NF + c] : (kr == 50 ? W_e1[178 * NF + c] : 0.f);
                val[i] = f2bfs(f);
            }
            *(short8*)(&wpack[WS_WE1R + s * 8]) = val;
        } else if (s < 1152) {        // W_e2 (nt 0..3) + We2s head-replicated (nt 4)
            int u = s - 512;
            int cl = u & 15, g = (u >> 4) & 3, q = u >> 6;
            int ks = q & 1, nt = q >> 1;
            int c = nt * 16 + cl, k0 = 32 * ks + 8 * g;
#pragma unroll
            for (int i = 0; i < 8; i++) {
                int k = k0 + i;
                float f;
                if (c < 64) f = W_e2[k * NF + c];
                else {
                    int cc = (c - 64) & 3;
                    f = 0.f;
                    for (int m = 0; m < 64; m++) f += W_e2[k * NF + m] * W_sem[m * NH + cc];
                }
                val[i] = f2bfs(f);
            }
            *(short8*)(&wpack[WS_WE2 + u * 8]) = val;
        } else {                      // W_xmix per-head: V_h[f,c]; [ct][h][ks][lane]
            int u = s - 1152;
            int l2 = u & 63, ks = (u >> 6) & 1, hh = (u >> 7) & 3, ct = u >> 9;
            int lr2 = l2 & 15, lg2 = l2 >> 4;
            int c = ct * 16 + lr2, k0 = ks * 32 + lg2 * 8;
#pragma unroll
            for (int i = 0; i < 8; i++)
                val[i] = f2bfs(W_xmix[((k0 + i) * 4 + hh) * NC + c]);
            *(short8*)(&wpack[WS_WX + u * 8]) = val;
        }
    } else if (blk == 37) {
        if (t < 4) {
            float acc = b_sem[t];
            for (int m = 0; m < 64; m++) acc += b_e2[m] * W_sem[m * NH + t];
            bs2[t] = acc;
        }
    } else {
        // wave-per-node precompute: 256 blocks x 4 nodes
        int w = t >> 6, l = t & 63;
        int node = (blk - 38) * 4 + w;
        __shared__ float s_hn[4][64];
        s_hn[w][l] = h[node * NF + l];
        // wave-local LDS write->read: ordered by lgkmcnt within the wave
        float a0 = 0.f, a1 = b_e1[l];
#pragma unroll 8
        for (int k = 0; k < 64; k++) {
            float hv = s_hn[w][k];
            a0 += hv * W_e1[k * NF + l];
            a1 += hv * W_e1[(64 + k) * NF + l];
        }
        e1[node * 128 + l] = a0;
        e1[node * 128 + 64 + l] = a1;
        if (l < 50) {
            float m0 = 0.f, m1 = b_in[l];
#pragma unroll 8
            for (int k = 0; k < 64; k++) {
                float hv = s_hn[w][k];
                m0 += hv * W_in[k * NR + l];
                m1 += hv * W_in[(64 + k) * NR + l];
            }
            mid[node * 128 + l] = m0;
            mid[node * 128 + 64 + l] = m1;
        }
    }
}

// =============== fused edge + tail: one block per (b,i) ===============
__global__ __launch_bounds__(256)
void sake_fused_kernel(
    const float* __restrict__ h, const float* __restrict__ x, const float* __restrict__ vin,
    const float* __restrict__ mid, const float* __restrict__ e1,
    const float* __restrict__ rbf_means, const float* __restrict__ rbf_betas,
    const float* __restrict__ b_e2, const float* __restrict__ bs2,
    const float* __restrict__ log_gamma,
    const short* __restrict__ wpack,
    const float* __restrict__ W_post1, const float* __restrict__ b_post1,
    const float* __restrict__ W_post2, const float* __restrict__ b_post2,
    const float* __restrict__ W_node1, const float* __restrict__ b_node1,
    const float* __restrict__ W_node2, const float* __restrict__ b_node2,
    const float* __restrict__ W_vel1, const float* __restrict__ b_vel1,
    const float* __restrict__ W_vel2, const float* __restrict__ W_vmix,
    float* __restrict__ out_h, float* __restrict__ out_x, float* __restrict__ out_v)
{
    const int bi = blockIdx.x;
    const int b  = bi >> 6;
    const int i  = bi & 63;
    const int t  = threadIdx.x;
    const int w  = t >> 6, l = t & 63, lr = l & 15, lg = l >> 4;

    __shared__ __align__(16) short s_A[16 * 64 * 8];   // 16 KiB; aliased as f32 SP after P3
    __shared__ __align__(16) short s_he[64 * 72];      // 9 KiB
    __shared__ float s_xhat[256];
    __shared__ float s_att[256];
    __shared__ float s_midi[52];

    const short8* A8  = (const short8*)s_A;
    short8*       A8w = (short8*)s_A;
    float*        SP  = (float*)s_A;
    const short8* We1p = (const short8*)(wpack + WS_WE1R);
    const short8* We2p = (const short8*)(wpack + WS_WE2);
    const short8* Wxp  = (const short8*)(wpack + WS_WX);

    // ---------- P0 ----------
    if (t < 50) s_midi[t] = mid[(b * 64 + i) * 128 + 64 + t];
    if (t < 64) {
        int j = t;
        float dx = x[(b * NN + j) * 3 + 0] - x[(b * NN + i) * 3 + 0];
        float dy = x[(b * NN + j) * 3 + 1] - x[(b * NN + i) * 3 + 1];
        float dz = x[(b * NN + j) * 3 + 2] - x[(b * NN + i) * 3 + 2];
        float d2 = dx * dx + dy * dy + dz * dz;
        float d  = sqrtf(fmaxf(d2, 0.f) + 1e-5f);
        float inv = 1.f / (d + 1e-5f);
        s_xhat[j * 4 + 0] = dx * inv;
        s_xhat[j * 4 + 1] = dy * inv;
        s_xhat[j * 4 + 2] = dz * inv;
        s_xhat[j * 4 + 3] = d;
    }
    __syncthreads();

    // ---------- early global loads ----------
    const int fW = w * 16 + lr;
    const float* e1b = e1 + (size_t)b * 64 * 128;
    float e1i_v = e1b[i * 128 + 64 + fW];
    float e1v[4][4];
#pragma unroll
    for (int jt = 0; jt < 4; jt++)
#pragma unroll
        for (int r = 0; r < 4; r++)
            e1v[jt][r] = e1b[(jt * 16 + lg * 4 + r) * 128 + fW];
    float be2 = b_e2[fW];
    float gam = __expf(log_gamma[lr & 3]);
    float bsv = bs2[lr & 3];

    // ---------- P1: rbf A slots 0..7 ----------
    {
        int j = t & 63, p = t >> 6;
        float d = s_xhat[j * 4 + 3];
        float cut = 0.5f * (__cosf(d * 0.6283185307179586f) + 1.f) * (d < 5.f ? 1.f : 0.f);
        float emd = __expf(-d);
        const float* mj = mid + (size_t)(b * 64 + j) * 128;
#pragma unroll
        for (int q = 0; q < 2; q++) {
            int sl = 2 * p + q;
            short8 val;
#pragma unroll
            for (int e = 0; e < 8; e++) {
                int r = sl * 8 + e;
                float o;
                if (r < 50) {
                    float m = mj[r] + s_midi[r];
                    float df = emd - rbf_means[r];
                    o = cut * __expf(-rbf_betas[r] * df * df) * m;
                } else if (r == 50) o = d;
                else o = 0.f;
                val[e] = f2bfs(o);
            }
            A8w[sl * 64 + j] = val;
        }
    }
    __syncthreads();

    // ---------- P2 (MFMA K=64, C-init E1j+E1i): u -> slots 8..15 ----------
    {
        f32x4 acc[4];
#pragma unroll
        for (int jt = 0; jt < 4; jt++)
#pragma unroll
            for (int r = 0; r < 4; r++) acc[jt][r] = e1v[jt][r] + e1i_v;
#pragma unroll
        for (int ks = 0; ks < 2; ks++) {
            short8 bb = We1p[(w * 2 + ks) * 64 + l];
#pragma unroll
            for (int jt = 0; jt < 4; jt++) {
                short8 aa = A8[(ks * 4 + lg) * 64 + jt * 16 + lr];
                acc[jt] = __builtin_amdgcn_mfma_f32_16x16x32_bf16(aa, bb, acc[jt], 0, 0, 0);
            }
        }
#pragma unroll
        for (int jt = 0; jt < 4; jt++)
#pragma unroll
            for (int r = 0; r < 4; r++) {
                int j = jt * 16 + lg * 4 + r;
                s_A[(((fW >> 3) + 8) * 64 + j) * 8 + (fW & 7)] = f2bfs(siluf(acc[jt][r]));
            }
        __syncthreads();
    }

    // ---------- P3: h_e -> s_he; wave 0: sem MFMA + in-register softmax -> s_att ----------
    {
        f32x4 accE[4], accS[4];
#pragma unroll
        for (int jt = 0; jt < 4; jt++) {
            accE[jt][0] = 0.f; accE[jt][1] = 0.f; accE[jt][2] = 0.f; accE[jt][3] = 0.f;
            accS[jt][0] = 0.f; accS[jt][1] = 0.f; accS[jt][2] = 0.f; accS[jt][3] = 0.f;
        }
#pragma unroll
        for (int ks = 0; ks < 2; ks++) {
            short8 aa[4];
#pragma unroll
            for (int jt = 0; jt < 4; jt++) aa[jt] = A8[(8 + ks * 4 + lg) * 64 + jt * 16 + lr];
            short8 bb = We2p[(w * 2 + ks) * 64 + l];
#pragma unroll
            for (int jt = 0; jt < 4; jt++)
                accE[jt] = __builtin_amdgcn_mfma_f32_16x16x32_bf16(aa[jt], bb, accE[jt], 0, 0, 0);
            if (w == 0) {
                short8 bb2 = We2p[(8 + ks) * 64 + l];
#pragma unroll
                for (int jt = 0; jt < 4; jt++)
                    accS[jt] = __builtin_amdgcn_mfma_f32_16x16x32_bf16(aa[jt], bb2, accS[jt], 0, 0, 0);
            }
        }
#pragma unroll
        for (int jt = 0; jt < 4; jt++)
#pragma unroll
            for (int r = 0; r < 4; r++) {
                int j = jt * 16 + lg * 4 + r;
                s_he[j * 72 + fW] = f2bfs(accE[jt][r] + be2);
            }
        if (w == 0) {
            float cel[4][4], dj[4][4];
            float m1 = -1e30f, m2 = -1e30f;
#pragma unroll
            for (int jt = 0; jt < 4; jt++)
#pragma unroll
                for (int r = 0; r < 4; r++) {
                    int j = jt * 16 + lg * 4 + r;
                    float s = accS[jt][r] + bsv;
                    float c = fmaxf(s, 0.f) + fminf(0.f, 2.f * (__expf(0.5f * s) - 1.f));
                    float d = s_xhat[j * 4 + 3];
                    if (j == i) { c -= 1e5f; d += 1e5f; }
                    cel[jt][r] = c; dj[jt][r] = d;
                    m1 = fmaxf(m1, c);
                    m2 = fmaxf(m2, -d * gam);
                }
            m1 = fmaxf(m1, __shfl_xor(m1, 16)); m1 = fmaxf(m1, __shfl_xor(m1, 32));
            m2 = fmaxf(m2, __shfl_xor(m2, 16)); m2 = fmaxf(m2, __shfl_xor(m2, 32));
            float S1 = 0.f, S2 = 0.f;
#pragma unroll
            for (int jt = 0; jt < 4; jt++)
#pragma unroll
                for (int r = 0; r < 4; r++) {
                    float ev1 = __expf(cel[jt][r] - m1);
                    float ev2 = __expf(-dj[jt][r] * gam - m2);
                    cel[jt][r] = ev1; dj[jt][r] = ev2;
                    S1 += ev1; S2 += ev2;
                }
            S1 += __shfl_xor(S1, 16); S1 += __shfl_xor(S1, 32);
            S2 += __shfl_xor(S2, 16); S2 += __shfl_xor(S2, 32);
            float inv12 = 1.f / (S1 * S2);
            float at[4][4];
            float S3 = 0.f;
#pragma unroll
            for (int jt = 0; jt < 4; jt++)
#pragma unroll
                for (int r = 0; r < 4; r++) {
                    at[jt][r] = cel[jt][r] * dj[jt][r] * inv12;
                    S3 += at[jt][r];
                }
            S3 += __shfl_xor(S3, 16); S3 += __shfl_xor(S3, 32);
            float inv3 = 1.f / S3;
            if (lr < 4) {
#pragma unroll
                for (int jt = 0; jt < 4; jt++)
#pragma unroll
                    for (int r = 0; r < 4; r++) {
                        int j = jt * 16 + lg * 4 + r;
                        s_att[j * 4 + lr] = at[jt][r] * inv3;
                    }
            }
        }
        __syncthreads();   // s_A (SP region) free from here
    }

    // ---------- P5: hagg -> SP_IN[64..319]; stage h_i -> SP_IN[0..63] ----------
    {
        if (t < 64) SP[SP_IN + t] = h[bi * 64 + t];
        int f2 = t >> 3, hh = (t >> 1) & 3, jh = t & 1;
        float a0 = 0.f, a1 = 0.f;
#pragma unroll 8
        for (int jj = 0; jj < 32; jj++) {
            int j = jh * 32 + jj;
            float at = s_att[j * 4 + hh];
            unsigned u = *(const unsigned*)(s_he + j * 72 + 2 * f2);
            a0 += bflo(u) * at;
            a1 += bfhi(u) * at;
        }
        a0 += __shfl_xor(a0, 1);
        a1 += __shfl_xor(a1, 1);
        if (!jh) {
            SP[SP_IN + 64 + (2 * f2) * 4 + hh]     = a0;
            SP[SP_IN + 64 + (2 * f2 + 1) * 4 + hh] = a1;
        }
    }

    // ---------- P6: per-head GEMM, A = att_h * h_e built in registers ----------
    {
        f32x4 acc[4][4];
#pragma unroll
        for (int jt = 0; jt < 4; jt++)
#pragma unroll
            for (int ct = 0; ct < 4; ct++) {
                acc[jt][ct][0] = 0.f; acc[jt][ct][1] = 0.f;
                acc[jt][ct][2] = 0.f; acc[jt][ct][3] = 0.f;
            }
#pragma unroll 1
        for (int hh = 0; hh < 4; hh++) {
            float ah[4];
#pragma unroll
            for (int jt = 0; jt < 4; jt++) ah[jt] = s_att[(jt * 16 + lr) * 4 + hh];
#pragma unroll
            for (int ks = 0; ks < 2; ks++) {
                short8 fr[4];
#pragma unroll
                for (int jt = 0; jt < 4; jt++) {
                    short8 he8 = *(const short8*)(s_he + (jt * 16 + lr) * 72 + ks * 32 + lg * 8);
                    short8 vv;
#pragma unroll
                    for (int e = 0; e < 8; e++) vv[e] = f2bfs(bf1((ushort)he8[e]) * ah[jt]);
                    fr[jt] = vv;
                }
#pragma unroll
                for (int ct = 0; ct < 4; ct++) {
                    short8 bb = Wxp[(((w * 4 + ct) * 4 + hh) * 2 + ks) * 64 + l];
#pragma unroll
                    for (int jt = 0; jt < 4; jt++)
                        acc[jt][ct] = __builtin_amdgcn_mfma_f32_16x16x32_bf16(fr[jt], bb, acc[jt][ct], 0, 0, 0);
                }
            }
        }
        // epilogue: tanh, xhat-weight, j-reduce -> SP_COMB [k][256] + SP_HCP
#pragma unroll
        for (int ct = 0; ct < 4; ct++) {
            float p0 = 0.f, p1 = 0.f, p2 = 0.f;
#pragma unroll
            for (int jt = 0; jt < 4; jt++)
#pragma unroll
                for (int r = 0; r < 4; r++) {
                    int j = jt * 16 + lg * 4 + r;
                    float4 xh = *(const float4*)(s_xhat + j * 4);
                    float th = tanhfast(acc[jt][ct][r]);
                    p0 += xh.x * th;
                    p1 += xh.y * th;
                    p2 += xh.z * th;
                }
            p0 += __shfl_xor(p0, 16); p0 += __shfl_xor(p0, 32);
            p1 += __shfl_xor(p1, 16); p1 += __shfl_xor(p1, 32);
            p2 += __shfl_xor(p2, 16); p2 += __shfl_xor(p2, 32);
            if (lg == 0) {
                int c = (w * 4 + ct) * 16 + lr;
                float c0 = p0 * (1.f / 64.f);
                float c1 = p1 * (1.f / 64.f);
                float c2 = p2 * (1.f / 64.f);
                SP[SP_COMB + c]       = c0;
                SP[SP_COMB + 256 + c] = c1;
                SP[SP_COMB + 512 + c] = c2;
                SP[SP_HCP + c] = c0 * c0 + c1 * c1 + c2 * c2;
            }
        }
    }
    __syncthreads();

    // ================= integrated tail (f32, wave-split K) =================
    const int f = l;
    // B1: post1 partials (K=256, 64 per wave)
    {
        float p = 0.f;
#pragma unroll 8
        for (int k = w * 64; k < w * 64 + 64; k++) p += SP[SP_HCP + k] * W_post1[k * NF + f];
        SP[SP_RED + w * 64 + f] = p;
    }
    __syncthreads();
    // B2: combine -> VEC
    if (w == 0) {
        float a = b_post1[f] + SP[SP_RED + f] + SP[SP_RED + 64 + f]
                + SP[SP_RED + 128 + f] + SP[SP_RED + 192 + f];
        SP[SP_VEC + f] = siluf(a);
    }
    __syncthreads();
    // B3: post2 full dot (redundant across waves) -> hcomb
    {
        float a = b_post2[f];
#pragma unroll 8
        for (int k = 0; k < 64; k++) a += SP[SP_VEC + k] * W_post2[k * NF + f];
        if (w == 0) SP[SP_IN + 320 + f] = siluf(a);
    }
    __syncthreads();
    // B4: node1 partials (K=384, 96 per wave)
    {
        float p = 0.f;
#pragma unroll 8
        for (int k = w * 96; k < w * 96 + 96; k++) p += SP[SP_IN + k] * W_node1[k * NF + f];
        SP[SP_RED + w * 64 + f] = p;
    }
    __syncthreads();
    // B5: combine -> VEC
    if (w == 0) {
        float a = b_node1[f] + SP[SP_RED + f] + SP[SP_RED + 64 + f]
                + SP[SP_RED + 128 + f] + SP[SP_RED + 192 + f];
        SP[SP_VEC + f] = siluf(a);
    }
    __syncthreads();
    // B6: node2 full dot + residual -> out_h, HO
    {
        float a = b_node2[f];
#pragma unroll 8
        for (int k = 0; k < 64; k++) a += SP[SP_VEC + k] * W_node2[k * NF + f];
        if (w == 0) {
            float ho = SP[SP_IN + f] + siluf(a);
            out_h[bi * NF + f] = ho;
            SP[SP_HO + f] = ho;
        }
    }
    __syncthreads();
    // B7: wave0 gate; waves 1-3 delta_v
    {
        if (w == 0) {
            float a = b_vel1[f];
#pragma unroll 8
            for (int k = 0; k < 64; k++) a += SP[SP_HO + k] * W_vel1[k * NF + f];
            float pv = siluf(a) * W_vel2[f];
            float g = wave_sum(pv);
            if (f == 0) SP[SP_MISC + 0] = 2.f / (1.f + __expf(-g));
        } else {
            int k3 = w - 1;
            float p = 0.f;
#pragma unroll
            for (int q = 0; q < 4; q++)
                p += SP[SP_COMB + k3 * 256 + q * 64 + f] * W_vmix[q * 64 + f];
            float dv = wave_sum(p);
            if (f == 0) SP[SP_MISC + w] = dv;
        }
    }
    __syncthreads();
    // B8: outputs
    if (t < 3) {
        float vout = SP[SP_MISC + 1 + t] + SP[SP_MISC + 0] * vin[bi * 3 + t];
        out_v[bi * 3 + t] = vout;
        out_x[bi * 3 + t] = x[bi * 3 + t] + vout;
    }
}

extern "C" void kernel_launch(void* const* d_in, const int* in_sizes, int n_in,
                              void* d_out, int out_size, void* d_ws, size_t ws_size,
                              hipStream_t stream) {
    const float* h        = (const float*)d_in[0];
    const float* x        = (const float*)d_in[1];
    const float* v        = (const float*)d_in[2];
    const float* W_in     = (const float*)d_in[3];
    const float* b_in     = (const float*)d_in[4];
    const float* rbf_m    = (const float*)d_in[5];
    const float* rbf_b    = (const float*)d_in[6];
    const float* W_e1     = (const float*)d_in[7];
    const float* b_e1     = (const float*)d_in[8];
    const float* W_e2     = (const float*)d_in[9];
    const float* b_e2     = (const float*)d_in[10];
    const float* W_sem    = (const float*)d_in[11];
    const float* b_sem    = (const float*)d_in[12];
    const float* log_g    = (const float*)d_in[13];
    const float* W_xmix   = (const float*)d_in[14];
    const float* W_post1  = (const float*)d_in[15];
    const float* b_post1  = (const float*)d_in[16];
    const float* W_post2  = (const float*)d_in[17];
    const float* b_post2  = (const float*)d_in[18];
    const float* W_node1  = (const float*)d_in[19];
    const float* b_node1  = (const float*)d_in[20];
    const float* W_node2  = (const float*)d_in[21];
    const float* b_node2  = (const float*)d_in[22];
    const float* W_vel1   = (const float*)d_in[23];
    const float* b_vel1   = (const float*)d_in[24];
    const float* W_vel2   = (const float*)d_in[25];
    const float* W_vmix   = (const float*)d_in[26];

    float* out   = (float*)d_out;
    float* out_h = out;
    float* out_x = out + NB * NN * NF;
    float* out_v = out + NB * NN * NF + NB * NN * 3;

    short* wpack = (short*)d_ws;
    float* wsf   = (float*)d_ws;
    float* mid   = wsf + MID_F;
    float* e1    = wsf + E1_F;
    float* bs2   = wsf + BS2_F;

    prep_kernel<<<38 + 256, 256, 0, stream>>>(
        W_e1, b_e1, W_e2, b_e2, W_sem, b_sem, W_xmix,
        h, W_in, b_in, wpack, mid, e1, bs2);

    sake_fused_kernel<<<NB * NN, 256, 0, stream>>>(
        h, x, v, mid, e1, rbf_m, rbf_b, b_e2, bs2, log_g, wpack,
        W_post1, b_post1, W_post2, b_post2, W_node1, b_node1,
        W_node2, b_node2, W_vel1, b_vel1, W_vel2, W_vmix,
        out_h, out_x, out_v);
}

// Round 11
// 56.718 us; speedup vs baseline: 1.1982x; 1.1982x over previous
//
#include <hip/hip_runtime.h>
#include <math.h>

#define NB 16
#define NN 64
#define NF 64
#define NH 4
#define NR 50
#define NC 256

typedef __attribute__((ext_vector_type(8))) short short8;
typedef __attribute__((ext_vector_type(4))) float f32x4;

// ws layout (shorts): We1rbf (512 slots) | We2 (512) | Wx (8192); then floats: mid | e1 | hagg | comb
#define WS_WE1R 0
#define WS_WE2  4096
#define WS_WX   8192
#define MID_F   36864                  // 1024 nodes x 128 (midj | midi), row-major
#define E1_F    (MID_F + 131072)       // 1024 x 128 (E1j | E1i+b)
#define HAGG_F  (E1_F + 131072)        // 1024 x 256
#define COMB_F  (HAGG_F + 262144)      // 1024 x 768

__device__ __forceinline__ float siluf(float x) { return x / (1.f + __expf(-x)); }
__device__ __forceinline__ float tanhfast(float x) { return 1.f - 2.f / (__expf(2.f * x) + 1.f); }

__device__ __forceinline__ short f2bfs(float f) {
    __bf16 b = (__bf16)f;
    union { __bf16 b; short s; } u; u.b = b; return u.s;
}
__device__ __forceinline__ float bf1(ushort u) {
    union { unsigned u; float f; } c; c.u = ((unsigned)u) << 16; return c.f;
}
__device__ __forceinline__ float bflo(unsigned u) {
    union { unsigned u; float f; } c; c.u = u << 16; return c.f;
}
__device__ __forceinline__ float bfhi(unsigned u) {
    union { unsigned u; float f; } c; c.u = u & 0xFFFF0000u; return c.f;
}

__device__ __forceinline__ float wave_max(float v) {
#pragma unroll
    for (int s = 32; s >= 1; s >>= 1) v = fmaxf(v, __shfl_xor(v, s));
    return v;
}
__device__ __forceinline__ float wave_sum(float v) {
#pragma unroll
    for (int s = 32; s >= 1; s >>= 1) v += __shfl_xor(v, s);
    return v;
}

// ---- prep: pack weights bf16 fragment-major + per-node precomputes (wave-per-node) ----
__global__ __launch_bounds__(256)
void prep_kernel(const float* __restrict__ W_e1, const float* __restrict__ b_e1,
                 const float* __restrict__ W_e2, const float* __restrict__ W_xmix,
                 const float* __restrict__ h, const float* __restrict__ W_in,
                 const float* __restrict__ b_in,
                 short* __restrict__ wpack, float* __restrict__ mid, float* __restrict__ e1)
{
    int blk = blockIdx.x, t = threadIdx.x;
    if (blk < 36) {
        int s = blk * 256 + t;   // 0..9215
        short8 val;
        if (s < 512) {                // W_e1 rbf part: K=64 (50 rbf + d), N=64
            int cl = s & 15, g = (s >> 4) & 3, q = s >> 6;
            int ks = q & 1, nt = q >> 1;
            int c = nt * 16 + cl, k0 = 32 * ks + 8 * g;
#pragma unroll
            for (int i = 0; i < 8; i++) {
                int kr = k0 + i;
                float f = (kr < 50) ? W_e1[(128 + kr) * NF + c] : (kr == 50 ? W_e1[178 * NF + c] : 0.f);
                val[i] = f2bfs(f);
            }
            *(short8*)(&wpack[WS_WE1R + s * 8]) = val;
        } else if (s < 1024) {        // W_e2: K=64, N=64
            int u = s - 512;
            int cl = u & 15, g = (u >> 4) & 3, q = u >> 6;
            int ks = q & 1, nt = q >> 1;
            int c = nt * 16 + cl, k0 = 32 * ks + 8 * g;
#pragma unroll
            for (int i = 0; i < 8; i++) val[i] = f2bfs(W_e2[(k0 + i) * NF + c]);
            *(short8*)(&wpack[WS_WE2 + u * 8]) = val;
        } else {                      // W_xmix: K=256, N=256
            int u = s - 1024;
            int cl = u & 15, g = (u >> 4) & 3, q = u >> 6;
            int ks = q & 7, wn = q >> 3;
            int c = (wn >> 2) * 64 + (wn & 3) * 16 + cl, k0 = 32 * ks + 8 * g;
#pragma unroll
            for (int i = 0; i < 8; i++) val[i] = f2bfs(W_xmix[(k0 + i) * NC + c]);
            *(short8*)(&wpack[WS_WX + u * 8]) = val;
        }
    } else {
        // wave-per-node precompute: 256 blocks x 4 nodes (validated r10; prep-local change)
        int w = t >> 6, l = t & 63;
        int node = (blk - 36) * 4 + w;
        __shared__ float s_hn[4][64];
        s_hn[w][l] = h[node * NF + l];
        // wave-local LDS write->read ordered by lgkmcnt within the wave
        float a0 = 0.f, a1 = b_e1[l];
#pragma unroll 8
        for (int k = 0; k < 64; k++) {
            float hv = s_hn[w][k];
            a0 += hv * W_e1[k * NF + l];
            a1 += hv * W_e1[(64 + k) * NF + l];
        }
        e1[node * 128 + l] = a0;
        e1[node * 128 + 64 + l] = a1;
        if (l < 50) {
            float m0 = 0.f, m1 = b_in[l];
#pragma unroll 8
            for (int k = 0; k < 64; k++) {
                float hv = s_hn[w][k];
                m0 += hv * W_in[k * NR + l];
                m1 += hv * W_in[(64 + k) * NR + l];
            }
            mid[node * 128 + l] = m0;
            mid[node * 128 + 64 + l] = m1;
        }
    }
}

// ---- main: one block per (b,i); edge model + attention + xmix GEMM (r3 verbatim, 56.05us config) ----
__global__ __launch_bounds__(256)
void sake_edge_kernel(
    const float* __restrict__ x,
    const float* __restrict__ mid, const float* __restrict__ e1,
    const float* __restrict__ rbf_means, const float* __restrict__ rbf_betas,
    const float* __restrict__ b_e1, const float* __restrict__ b_e2,
    const float* __restrict__ W_sem, const float* __restrict__ b_sem,
    const float* __restrict__ log_gamma,
    const short* __restrict__ wpack,
    float* __restrict__ hagg_g, float* __restrict__ comb_g)
{
    const int bi = blockIdx.x;
    const int b  = bi >> 6;
    const int i  = bi & 63;
    const int t  = threadIdx.x;
    const int w  = t >> 6, l = t & 63, lr = l & 15, lg = l >> 4;

    __shared__ __align__(16) short s_A[16 * 64 * 8];   // 16 KiB: A staging (fragment-major)
    __shared__ short s_he[64 * 66];                    // 8.25 KiB: h_e bf16, stride 66
    __shared__ float s_comb[768];
    __shared__ float s_xhat[256];
    __shared__ float s_att[256];
    __shared__ float s_wsem[256];
    __shared__ float s_midi[52];

    const short8* A8  = (const short8*)s_A;
    short8*       A8w = (short8*)s_A;
    const short8* We1p = (const short8*)(wpack + WS_WE1R);
    const short8* We2p = (const short8*)(wpack + WS_WE2);
    const short8* Wxp  = (const short8*)(wpack + WS_WX);

    // ---------- P0: small staging ----------
    s_wsem[t] = W_sem[t];
    if (t < 50) s_midi[t] = mid[(b * 64 + i) * 128 + 64 + t];
    if (t < 64) {
        int j = t;
        float dx = x[(b * NN + j) * 3 + 0] - x[(b * NN + i) * 3 + 0];
        float dy = x[(b * NN + j) * 3 + 1] - x[(b * NN + i) * 3 + 1];
        float dz = x[(b * NN + j) * 3 + 2] - x[(b * NN + i) * 3 + 2];
        float d2 = dx * dx + dy * dy + dz * dz;
        float d  = sqrtf(fmaxf(d2, 0.f) + 1e-5f);
        float inv = 1.f / (d + 1e-5f);
        s_xhat[j * 4 + 0] = dx * inv;
        s_xhat[j * 4 + 1] = dy * inv;
        s_xhat[j * 4 + 2] = dz * inv;
        s_xhat[j * 4 + 3] = d;
    }
    __syncthreads();

    // ---------- P1: build A slots: 0..7 rbf*h_mid,d,0 (K=64) ----------
    {
        int j = t & 63, p = t >> 6;
        float d = s_xhat[j * 4 + 3];
        float cut = 0.5f * (__cosf(d * 0.6283185307179586f) + 1.f) * (d < 5.f ? 1.f : 0.f);
        float emd = __expf(-d);
        const float* midj = mid + (b * 64 + j) * 128;
#pragma unroll
        for (int q = 0; q < 2; q++) {
            int sl = 2 * p + q;
            short8 val;
#pragma unroll
            for (int e = 0; e < 8; e++) {
                int r = sl * 8 + e;   // 0..63
                float o;
                if (r < 50) {
                    float m = midj[r] + s_midi[r];
                    float df = emd - rbf_means[r];
                    o = cut * __expf(-rbf_betas[r] * df * df) * m;
                } else if (r == 50) o = d;
                else o = 0.f;
                val[e] = f2bfs(o);
            }
            A8w[sl * 64 + j] = val;
        }
    }
    __syncthreads();

    // ---------- P2 (MFMA K=64, C-init = E1j+E1i): u = silu(...) -> A slots 0..7 ----------
    {
        int f = w * 16 + lr;
        const float* e1b = e1 + (size_t)b * 64 * 128;
        float e1i_v = e1b[i * 128 + 64 + f];
        f32x4 acc[4];
#pragma unroll
        for (int jt = 0; jt < 4; jt++)
#pragma unroll
            for (int r = 0; r < 4; r++) {
                int j = jt * 16 + lg * 4 + r;
                acc[jt][r] = e1b[j * 128 + f] + e1i_v;
            }
#pragma unroll
        for (int ks = 0; ks < 2; ks++) {
            short8 bb = We1p[(w * 2 + ks) * 64 + l];
#pragma unroll
            for (int jt = 0; jt < 4; jt++) {
                short8 aa = A8[(ks * 4 + lg) * 64 + jt * 16 + lr];
                acc[jt] = __builtin_amdgcn_mfma_f32_16x16x32_bf16(aa, bb, acc[jt], 0, 0, 0);
            }
        }
        __syncthreads();   // all rbf-A reads done before overwrite with u
#pragma unroll
        for (int jt = 0; jt < 4; jt++)
#pragma unroll
            for (int r = 0; r < 4; r++) {
                int j = jt * 16 + lg * 4 + r;
                s_A[((f >> 3) * 64 + j) * 8 + (f & 7)] = f2bfs(siluf(acc[jt][r]));
            }
        __syncthreads();
    }

    // ---------- P3 (MFMA): h_e = u @ W_e2 + b_e2 -> s_he (bf16, stride 66) ----------
    {
        f32x4 acc[4];
#pragma unroll
        for (int jt = 0; jt < 4; jt++) { acc[jt][0] = 0.f; acc[jt][1] = 0.f; acc[jt][2] = 0.f; acc[jt][3] = 0.f; }
#pragma unroll
        for (int ks = 0; ks < 2; ks++) {
            short8 bb = We2p[(w * 2 + ks) * 64 + l];
#pragma unroll
            for (int jt = 0; jt < 4; jt++) {
                short8 aa = A8[(ks * 4 + lg) * 64 + jt * 16 + lr];
                acc[jt] = __builtin_amdgcn_mfma_f32_16x16x32_bf16(aa, bb, acc[jt], 0, 0, 0);
            }
        }
        float be2 = b_e2[w * 16 + lr];
        int f = w * 16 + lr;
#pragma unroll
        for (int jt = 0; jt < 4; jt++)
#pragma unroll
            for (int r = 0; r < 4; r++) {
                int j = jt * 16 + lg * 4 + r;
                s_he[j * 66 + f] = f2bfs(acc[jt][r] + be2);
            }
        __syncthreads();
    }

    // ---------- P4: sem/euc softmax over j ----------
    {
        int hh = w, j = l;
        float acc = b_sem[hh];
        const unsigned* hp = (const unsigned*)(s_he + j * 66);
#pragma unroll 8
        for (int q = 0; q < 32; q++) {
            unsigned u = hp[q];
            acc += bflo(u) * s_wsem[(2 * q) * 4 + hh] + bfhi(u) * s_wsem[(2 * q + 1) * 4 + hh];
        }
        float cel = fmaxf(acc, 0.f) + fminf(0.f, 2.f * (__expf(0.5f * acc) - 1.f));
        float diag = (j == i) ? 1e5f : 0.f;
        float slog = cel - diag;
        float m1 = wave_max(slog);
        float e1v = __expf(slog - m1);
        float sem = e1v / wave_sum(e1v);
        float gam = __expf(log_gamma[hh]);
        float elog = -(s_xhat[j * 4 + 3] + diag) * gam;
        float m2 = wave_max(elog);
        float e2 = __expf(elog - m2);
        float euc = e2 / wave_sum(e2);
        float a = sem * euc;
        a = a / wave_sum(a);
        s_att[j * 4 + hh] = a;
    }
    __syncthreads();

    // ---------- P5: h_agg -> global (c == t) ----------
    {
        int f = t >> 2, hh = t & 3;
        float acc = 0.f;
#pragma unroll 8
        for (int j = 0; j < 64; j++) acc += bf1((ushort)s_he[j * 66 + f]) * s_att[j * 4 + hh];
        hagg_g[bi * 256 + t] = acc;
    }

    // ---------- P6: xmix GEMM in two K-halves; A region reused ----------
    f32x4 acc[4][4];
#pragma unroll
    for (int jt = 0; jt < 4; jt++)
#pragma unroll
        for (int nt = 0; nt < 4; nt++) { acc[jt][nt][0] = 0.f; acc[jt][nt][1] = 0.f; acc[jt][nt][2] = 0.f; acc[jt][nt][3] = 0.f; }

    for (int half = 0; half < 2; half++) {
        {   // build hea slots 0..15 for k in [128*half, +128)
            int j = t & 63, kc = t >> 6;
            float a0 = s_att[j * 4 + 0], a1 = s_att[j * 4 + 1];
            float a2 = s_att[j * 4 + 2], a3 = s_att[j * 4 + 3];
#pragma unroll
            for (int s = 0; s < 4; s++) {
                int sl = kc * 4 + s;
                int kbase = half * 128 + sl * 8;
                unsigned u = *(const unsigned*)(s_he + j * 66 + (kbase >> 2));
                float h0 = bflo(u), h1 = bfhi(u);
                short8 val;
                val[0] = f2bfs(h0 * a0); val[1] = f2bfs(h0 * a1);
                val[2] = f2bfs(h0 * a2); val[3] = f2bfs(h0 * a3);
                val[4] = f2bfs(h1 * a0); val[5] = f2bfs(h1 * a1);
                val[6] = f2bfs(h1 * a2); val[7] = f2bfs(h1 * a3);
                A8w[sl * 64 + j] = val;
            }
        }
        __syncthreads();
#pragma unroll
        for (int ks = 0; ks < 4; ks++) {
            short8 aa[4], bb[4];
#pragma unroll
            for (int jt = 0; jt < 4; jt++) aa[jt] = A8[(ks * 4 + lg) * 64 + jt * 16 + lr];
#pragma unroll
            for (int nt = 0; nt < 4; nt++) bb[nt] = Wxp[((w * 4 + nt) * 8 + half * 4 + ks) * 64 + l];
#pragma unroll
            for (int jt = 0; jt < 4; jt++)
#pragma unroll
                for (int nt = 0; nt < 4; nt++)
                    acc[jt][nt] = __builtin_amdgcn_mfma_f32_16x16x32_bf16(aa[jt], bb[nt], acc[jt][nt], 0, 0, 0);
        }
        __syncthreads();
    }

    // epilogue: tanh, weight by x_hat, reduce over j -> comb (mean), direct to global
    {
#pragma unroll
        for (int nt = 0; nt < 4; nt++) {
            float p0 = 0.f, p1 = 0.f, p2 = 0.f;
#pragma unroll
            for (int jt = 0; jt < 4; jt++)
#pragma unroll
                for (int r = 0; r < 4; r++) {
                    int j = jt * 16 + lg * 4 + r;
                    float th = tanhfast(acc[jt][nt][r]);
                    p0 += s_xhat[j * 4 + 0] * th;
                    p1 += s_xhat[j * 4 + 1] * th;
                    p2 += s_xhat[j * 4 + 2] * th;
                }
            p0 += __shfl_xor(p0, 16); p0 += __shfl_xor(p0, 32);
            p1 += __shfl_xor(p1, 16); p1 += __shfl_xor(p1, 32);
            p2 += __shfl_xor(p2, 16); p2 += __shfl_xor(p2, 32);
            if (lg == 0) {
                int c = w * 64 + nt * 16 + lr;
                float* cg = comb_g + bi * 768 + c * 3;
                cg[0] = p0 * (1.f / 64.f);
                cg[1] = p1 * (1.f / 64.f);
                cg[2] = p2 * (1.f / 64.f);
            }
        }
    }
}

// ---- tail: per-node MLPs; ONE node per block, K-loops split across 4 waves (r3 verbatim) ----
__global__ __launch_bounds__(256)
void sake_tail_kernel(
    const float* __restrict__ h, const float* __restrict__ x, const float* __restrict__ v,
    const float* __restrict__ hagg_g, const float* __restrict__ comb_g,
    const float* __restrict__ W_post1, const float* __restrict__ b_post1,
    const float* __restrict__ W_post2, const float* __restrict__ b_post2,
    const float* __restrict__ W_node1, const float* __restrict__ b_node1,
    const float* __restrict__ W_node2, const float* __restrict__ b_node2,
    const float* __restrict__ W_vel1, const float* __restrict__ b_vel1,
    const float* __restrict__ W_vel2, const float* __restrict__ W_vmix,
    float* __restrict__ out_h, float* __restrict__ out_x, float* __restrict__ out_v)
{
    const int node = blockIdx.x;
    const int t = threadIdx.x, w = t >> 6, l = t & 63;

    __shared__ float s_in[384];      // [h | hagg | hcomb]
    __shared__ float s_hcp[256];
    __shared__ float s_cmb[3][256];
    __shared__ float s_red[4][64];
    __shared__ float s_vec[64];
    __shared__ float s_ho[64];

    {
        const float* cg = comb_g + node * 768;
        float c0 = cg[t * 3 + 0], c1 = cg[t * 3 + 1], c2 = cg[t * 3 + 2];
        s_cmb[0][t] = c0; s_cmb[1][t] = c1; s_cmb[2][t] = c2;
        s_hcp[t] = c0 * c0 + c1 * c1 + c2 * c2;
        if (t < 64) s_in[t] = h[node * NF + t];
        s_in[64 + t] = hagg_g[node * 256 + t];
    }
    __syncthreads();

    // post1: K=256, 64 k's per wave
    {
        float p = 0.f;
#pragma unroll 8
        for (int k = w * 64; k < w * 64 + 64; k++) p += s_hcp[k] * W_post1[k * NF + l];
        s_red[w][l] = p;
    }
    __syncthreads();
    {
        float a = b_post1[l] + s_red[0][l] + s_red[1][l] + s_red[2][l] + s_red[3][l];
        if (w == 0) s_vec[l] = siluf(a);
    }
    __syncthreads();

    // post2: K=64, 16 per wave -> h_comb
    {
        float p = 0.f;
#pragma unroll
        for (int k = w * 16; k < w * 16 + 16; k++) p += s_vec[k] * W_post2[k * NF + l];
        s_red[w][l] = p;
    }
    __syncthreads();
    {
        float a = b_post2[l] + s_red[0][l] + s_red[1][l] + s_red[2][l] + s_red[3][l];
        if (w == 0) s_in[320 + l] = siluf(a);
    }
    __syncthreads();

    // node1: K=384, 96 per wave
    {
        float p = 0.f;
#pragma unroll 8
        for (int k = w * 96; k < w * 96 + 96; k++) p += s_in[k] * W_node1[k * NF + l];
        s_red[w][l] = p;
    }
    __syncthreads();
    {
        float a = b_node1[l] + s_red[0][l] + s_red[1][l] + s_red[2][l] + s_red[3][l];
        if (w == 0) s_vec[l] = siluf(a);
    }
    __syncthreads();

    // node2 + residual -> h_out
    {
        float p = 0.f;
#pragma unroll
        for (int k = w * 16; k < w * 16 + 16; k++) p += s_vec[k] * W_node2[k * NF + l];
        s_red[w][l] = p;
    }
    __syncthreads();
    {
        float a = b_node2[l] + s_red[0][l] + s_red[1][l] + s_red[2][l] + s_red[3][l];
        float ho = s_in[l] + siluf(a);
        if (w == 0) { out_h[node * NF + l] = ho; s_ho[l] = ho; }
    }
    __syncthreads();

    // vel1
    {
        float p = 0.f;
#pragma unroll
        for (int k = w * 16; k < w * 16 + 16; k++) p += s_ho[k] * W_vel1[k * NF + l];
        s_red[w][l] = p;
    }
    __syncthreads();
    {
        float a = b_vel1[l] + s_red[0][l] + s_red[1][l] + s_red[2][l] + s_red[3][l];
        float v1 = siluf(a);
        float g = wave_sum(v1 * W_vel2[l]);
        g = 2.f / (1.f + __expf(-g));
        if (w < 3) {
            float pv = 0.f;
#pragma unroll
            for (int q = 0; q < 4; q++) pv += s_cmb[w][q * 64 + l] * W_vmix[q * 64 + l];
            float dv = wave_sum(pv);
            if (l == 0) {
                float vout = dv + g * v[node * 3 + w];
                out_v[node * 3 + w] = vout;
                out_x[node * 3 + w] = x[node * 3 + w] + vout;
            }
        }
    }
}

extern "C" void kernel_launch(void* const* d_in, const int* in_sizes, int n_in,
                              void* d_out, int out_size, void* d_ws, size_t ws_size,
                              hipStream_t stream) {
    const float* h        = (const float*)d_in[0];
    const float* x        = (const float*)d_in[1];
    const float* v        = (const float*)d_in[2];
    const float* W_in     = (const float*)d_in[3];
    const float* b_in     = (const float*)d_in[4];
    const float* rbf_m    = (const float*)d_in[5];
    const float* rbf_b    = (const float*)d_in[6];
    const float* W_e1     = (const float*)d_in[7];
    const float* b_e1     = (const float*)d_in[8];
    const float* W_e2     = (const float*)d_in[9];
    const float* b_e2     = (const float*)d_in[10];
    const float* W_sem    = (const float*)d_in[11];
    const float* b_sem    = (const float*)d_in[12];
    const float* log_g    = (const float*)d_in[13];
    const float* W_xmix   = (const float*)d_in[14];
    const float* W_post1  = (const float*)d_in[15];
    const float* b_post1  = (const float*)d_in[16];
    const float* W_post2  = (const float*)d_in[17];
    const float* b_post2  = (const float*)d_in[18];
    const float* W_node1  = (const float*)d_in[19];
    const float* b_node1  = (const float*)d_in[20];
    const float* W_node2  = (const float*)d_in[21];
    const float* b_node2  = (const float*)d_in[22];
    const float* W_vel1   = (const float*)d_in[23];
    const float* b_vel1   = (const float*)d_in[24];
    const float* W_vel2   = (const float*)d_in[25];
    const float* W_vmix   = (const float*)d_in[26];

    float* out   = (float*)d_out;
    float* out_h = out;
    float* out_x = out + NB * NN * NF;
    float* out_v = out + NB * NN * NF + NB * NN * 3;

    short* wpack = (short*)d_ws;
    float* wsf   = (float*)d_ws;
    float* mid   = wsf + MID_F;
    float* e1    = wsf + E1_F;
    float* hagg  = wsf + HAGG_F;
    float* comb  = wsf + COMB_F;

    prep_kernel<<<36 + 256, 256, 0, stream>>>(W_e1, b_e1, W_e2, W_xmix, h, W_in, b_in,
                                              wpack, mid, e1);

    sake_edge_kernel<<<NB * NN, 256, 0, stream>>>(
        x, mid, e1, rbf_m, rbf_b, b_e1, b_e2, W_sem, b_sem, log_g,
        wpack, hagg, comb);

    sake_tail_kernel<<<NB * NN, 256, 0, stream>>>(
        h, x, v, hagg, comb,
        W_post1, b_post1, W_post2, b_post2, W_node1, b_node1, W_node2, b_node2,
        W_vel1, b_vel1, W_vel2, W_vmix, out_h, out_x, out_v);
}

// Round 12
// 56.103 us; speedup vs baseline: 1.2113x; 1.0110x over previous
//
#include <hip/hip_runtime.h>
#include <math.h>

#define NB 16
#define NN 64
#define NF 64
#define NH 4
#define NR 50
#define NC 256

typedef __attribute__((ext_vector_type(8))) short short8;
typedef __attribute__((ext_vector_type(4))) float f32x4;

// ---- wpack short offsets (fragment-major bf16 weight packs) ----
#define WS_WE1R 0          // 512 entries  (K=64 rbf part of W_e1)
#define WS_WE2  4096       // 512          (K=64)
#define WS_WX   8192       // 8192         (K=256, N=256)
#define WS_PO1  73728      // 2048         (K=256, N=64)
#define WS_NO1  90112      // 3072         (K=384, N=64)
#define WS_PO2  114688     // 512
#define WS_NO2  118784     // 512
#define WS_VE1  122880     // 512 -> shorts end 126976
// ---- float offsets in ws ----
#define MID_F   65536                  // 1024 nodes x 128 (midj | midi), row-major
#define E1_F    (MID_F + 131072)       // 1024 x 128 (E1j | E1i+b)
#define HAGG_F  (E1_F + 131072)        // 1024 x 256
#define COMB_F  (HAGG_F + 262144)      // 1024 x 768

__device__ __forceinline__ float siluf(float x) { return x / (1.f + __expf(-x)); }
__device__ __forceinline__ float tanhfast(float x) { return 1.f - 2.f / (__expf(2.f * x) + 1.f); }

__device__ __forceinline__ short f2bfs(float f) {
    __bf16 b = (__bf16)f;
    union { __bf16 b; short s; } u; u.b = b; return u.s;
}
__device__ __forceinline__ float bf1(ushort u) {
    union { unsigned u; float f; } c; c.u = ((unsigned)u) << 16; return c.f;
}
__device__ __forceinline__ float bflo(unsigned u) {
    union { unsigned u; float f; } c; c.u = u << 16; return c.f;
}
__device__ __forceinline__ float bfhi(unsigned u) {
    union { unsigned u; float f; } c; c.u = u & 0xFFFF0000u; return c.f;
}

__device__ __forceinline__ float wave_max(float v) {
#pragma unroll
    for (int s = 32; s >= 1; s >>= 1) v = fmaxf(v, __shfl_xor(v, s));
    return v;
}
__device__ __forceinline__ float wave_sum(float v) {
#pragma unroll
    for (int s = 32; s >= 1; s >>= 1) v += __shfl_xor(v, s);
    return v;
}

// =============== prep: all weight packs (r4) + wave-per-node precompute (r11) ===============
__global__ __launch_bounds__(256)
void prep_kernel(const float* __restrict__ W_e1, const float* __restrict__ b_e1,
                 const float* __restrict__ W_e2, const float* __restrict__ W_xmix,
                 const float* __restrict__ W_post1, const float* __restrict__ W_node1,
                 const float* __restrict__ W_post2, const float* __restrict__ W_node2,
                 const float* __restrict__ W_vel1,
                 const float* __restrict__ h, const float* __restrict__ W_in,
                 const float* __restrict__ b_in,
                 short* __restrict__ wpack, float* __restrict__ mid, float* __restrict__ e1)
{
    int blk = blockIdx.x, t = threadIdx.x;
    if (blk < 62) {
        int s = blk * 256 + t;   // 0..15871
        short8 val;
        if (s < 512) {               // W_e1 rbf part: K=64 (50 rbf + d + pad)
            int cl = s & 15, g = (s >> 4) & 3, q = s >> 6;
            int ks = q & 1, nt = q >> 1;
            int c = nt * 16 + cl, k0 = 32 * ks + 8 * g;
#pragma unroll
            for (int i = 0; i < 8; i++) {
                int kr = k0 + i;
                float f = (kr < 50) ? W_e1[(128 + kr) * NF + c] : (kr == 50 ? W_e1[178 * NF + c] : 0.f);
                val[i] = f2bfs(f);
            }
            *(short8*)(&wpack[WS_WE1R + s * 8]) = val;
        } else if (s < 1024) {        // W_e2 K=64
            int u = s - 512;
            int cl = u & 15, g = (u >> 4) & 3, q = u >> 6;
            int ks = q & 1, nt = q >> 1;
            int c = nt * 16 + cl, k0 = 32 * ks + 8 * g;
#pragma unroll
            for (int i = 0; i < 8; i++) val[i] = f2bfs(W_e2[(k0 + i) * NF + c]);
            *(short8*)(&wpack[WS_WE2 + u * 8]) = val;
        } else if (s < 9216) {        // W_xmix K=256 N=256
            int u = s - 1024;
            int cl = u & 15, g = (u >> 4) & 3, q = u >> 6;
            int ks = q & 7, wn = q >> 3;
            int c = (wn >> 2) * 64 + (wn & 3) * 16 + cl, k0 = 32 * ks + 8 * g;
#pragma unroll
            for (int i = 0; i < 8; i++) val[i] = f2bfs(W_xmix[(k0 + i) * NC + c]);
            *(short8*)(&wpack[WS_WX + u * 8]) = val;
        } else if (s < 11264) {       // W_post1 K=256 N=64
            int u = s - 9216;
            int cl = u & 15, g = (u >> 4) & 3, q = u >> 6;
            int ks = q & 7, nt = q >> 3;
            int c = nt * 16 + cl, k0 = 32 * ks + 8 * g;
#pragma unroll
            for (int i = 0; i < 8; i++) val[i] = f2bfs(W_post1[(k0 + i) * NF + c]);
            *(short8*)(&wpack[WS_PO1 + u * 8]) = val;
        } else if (s < 14336) {       // W_node1 K=384 N=64
            int u = s - 11264;
            int cl = u & 15, g = (u >> 4) & 3, q = u >> 6;
            int ks = q % 12, nt = q / 12;
            int c = nt * 16 + cl, k0 = 32 * ks + 8 * g;
#pragma unroll
            for (int i = 0; i < 8; i++) val[i] = f2bfs(W_node1[(k0 + i) * NF + c]);
            *(short8*)(&wpack[WS_NO1 + u * 8]) = val;
        } else if (s < 14848) {       // W_post2 K=64
            int u = s - 14336;
            int cl = u & 15, g = (u >> 4) & 3, q = u >> 6;
            int ks = q & 1, nt = q >> 1;
            int c = nt * 16 + cl, k0 = 32 * ks + 8 * g;
#pragma unroll
            for (int i = 0; i < 8; i++) val[i] = f2bfs(W_post2[(k0 + i) * NF + c]);
            *(short8*)(&wpack[WS_PO2 + u * 8]) = val;
        } else if (s < 15360) {       // W_node2 K=64
            int u = s - 14848;
            int cl = u & 15, g = (u >> 4) & 3, q = u >> 6;
            int ks = q & 1, nt = q >> 1;
            int c = nt * 16 + cl, k0 = 32 * ks + 8 * g;
#pragma unroll
            for (int i = 0; i < 8; i++) val[i] = f2bfs(W_node2[(k0 + i) * NF + c]);
            *(short8*)(&wpack[WS_NO2 + u * 8]) = val;
        } else {                      // W_vel1 K=64
            int u = s - 15360;
            int cl = u & 15, g = (u >> 4) & 3, q = u >> 6;
            int ks = q & 1, nt = q >> 1;
            int c = nt * 16 + cl, k0 = 32 * ks + 8 * g;
#pragma unroll
            for (int i = 0; i < 8; i++) val[i] = f2bfs(W_vel1[(k0 + i) * NF + c]);
            *(short8*)(&wpack[WS_VE1 + u * 8]) = val;
        }
    } else {
        // wave-per-node precompute: 256 blocks x 4 nodes (validated r10/r11)
        int w = t >> 6, l = t & 63;
        int node = (blk - 62) * 4 + w;
        __shared__ float s_hn[4][64];
        s_hn[w][l] = h[node * NF + l];
        // wave-local LDS write->read ordered by lgkmcnt within the wave
        float a0 = 0.f, a1 = b_e1[l];
#pragma unroll 8
        for (int k = 0; k < 64; k++) {
            float hv = s_hn[w][k];
            a0 += hv * W_e1[k * NF + l];
            a1 += hv * W_e1[(64 + k) * NF + l];
        }
        e1[node * 128 + l] = a0;
        e1[node * 128 + 64 + l] = a1;
        if (l < 50) {
            float m0 = 0.f, m1 = b_in[l];
#pragma unroll 8
            for (int k = 0; k < 64; k++) {
                float hv = s_hn[w][k];
                m0 += hv * W_in[k * NR + l];
                m1 += hv * W_in[(64 + k) * NR + l];
            }
            mid[node * 128 + l] = m0;
            mid[node * 128 + 64 + l] = m1;
        }
    }
}

// =============== edge: r11 verbatim (reproduced 42.2us config) ===============
__global__ __launch_bounds__(256)
void sake_edge_kernel(
    const float* __restrict__ x,
    const float* __restrict__ mid, const float* __restrict__ e1,
    const float* __restrict__ rbf_means, const float* __restrict__ rbf_betas,
    const float* __restrict__ b_e1, const float* __restrict__ b_e2,
    const float* __restrict__ W_sem, const float* __restrict__ b_sem,
    const float* __restrict__ log_gamma,
    const short* __restrict__ wpack,
    float* __restrict__ hagg_g, float* __restrict__ comb_g)
{
    const int bi = blockIdx.x;
    const int b  = bi >> 6;
    const int i  = bi & 63;
    const int t  = threadIdx.x;
    const int w  = t >> 6, l = t & 63, lr = l & 15, lg = l >> 4;

    __shared__ __align__(16) short s_A[16 * 64 * 8];   // 16 KiB: A staging (fragment-major)
    __shared__ short s_he[64 * 66];                    // 8.25 KiB: h_e bf16, stride 66
    __shared__ float s_comb[768];
    __shared__ float s_xhat[256];
    __shared__ float s_att[256];
    __shared__ float s_wsem[256];
    __shared__ float s_midi[52];

    const short8* A8  = (const short8*)s_A;
    short8*       A8w = (short8*)s_A;
    const short8* We1p = (const short8*)(wpack + WS_WE1R);
    const short8* We2p = (const short8*)(wpack + WS_WE2);
    const short8* Wxp  = (const short8*)(wpack + WS_WX);

    // ---------- P0: small staging ----------
    s_wsem[t] = W_sem[t];
    if (t < 50) s_midi[t] = mid[(b * 64 + i) * 128 + 64 + t];
    if (t < 64) {
        int j = t;
        float dx = x[(b * NN + j) * 3 + 0] - x[(b * NN + i) * 3 + 0];
        float dy = x[(b * NN + j) * 3 + 1] - x[(b * NN + i) * 3 + 1];
        float dz = x[(b * NN + j) * 3 + 2] - x[(b * NN + i) * 3 + 2];
        float d2 = dx * dx + dy * dy + dz * dz;
        float d  = sqrtf(fmaxf(d2, 0.f) + 1e-5f);
        float inv = 1.f / (d + 1e-5f);
        s_xhat[j * 4 + 0] = dx * inv;
        s_xhat[j * 4 + 1] = dy * inv;
        s_xhat[j * 4 + 2] = dz * inv;
        s_xhat[j * 4 + 3] = d;
    }
    __syncthreads();

    // ---------- P1: build A slots: 0..7 rbf*h_mid,d,0 (K=64) ----------
    {
        int j = t & 63, p = t >> 6;
        float d = s_xhat[j * 4 + 3];
        float cut = 0.5f * (__cosf(d * 0.6283185307179586f) + 1.f) * (d < 5.f ? 1.f : 0.f);
        float emd = __expf(-d);
        const float* midj = mid + (b * 64 + j) * 128;
#pragma unroll
        for (int q = 0; q < 2; q++) {
            int sl = 2 * p + q;
            short8 val;
#pragma unroll
            for (int e = 0; e < 8; e++) {
                int r = sl * 8 + e;   // 0..63
                float o;
                if (r < 50) {
                    float m = midj[r] + s_midi[r];
                    float df = emd - rbf_means[r];
                    o = cut * __expf(-rbf_betas[r] * df * df) * m;
                } else if (r == 50) o = d;
                else o = 0.f;
                val[e] = f2bfs(o);
            }
            A8w[sl * 64 + j] = val;
        }
    }
    __syncthreads();

    // ---------- P2 (MFMA K=64, C-init = E1j+E1i): u = silu(...) -> A slots 0..7 ----------
    {
        int f = w * 16 + lr;
        const float* e1b = e1 + (size_t)b * 64 * 128;
        float e1i_v = e1b[i * 128 + 64 + f];
        f32x4 acc[4];
#pragma unroll
        for (int jt = 0; jt < 4; jt++)
#pragma unroll
            for (int r = 0; r < 4; r++) {
                int j = jt * 16 + lg * 4 + r;
                acc[jt][r] = e1b[j * 128 + f] + e1i_v;
            }
#pragma unroll
        for (int ks = 0; ks < 2; ks++) {
            short8 bb = We1p[(w * 2 + ks) * 64 + l];
#pragma unroll
            for (int jt = 0; jt < 4; jt++) {
                short8 aa = A8[(ks * 4 + lg) * 64 + jt * 16 + lr];
                acc[jt] = __builtin_amdgcn_mfma_f32_16x16x32_bf16(aa, bb, acc[jt], 0, 0, 0);
            }
        }
        __syncthreads();   // all rbf-A reads done before overwrite with u
#pragma unroll
        for (int jt = 0; jt < 4; jt++)
#pragma unroll
            for (int r = 0; r < 4; r++) {
                int j = jt * 16 + lg * 4 + r;
                s_A[((f >> 3) * 64 + j) * 8 + (f & 7)] = f2bfs(siluf(acc[jt][r]));
            }
        __syncthreads();
    }

    // ---------- P3 (MFMA): h_e = u @ W_e2 + b_e2 -> s_he (bf16, stride 66) ----------
    {
        f32x4 acc[4];
#pragma unroll
        for (int jt = 0; jt < 4; jt++) { acc[jt][0] = 0.f; acc[jt][1] = 0.f; acc[jt][2] = 0.f; acc[jt][3] = 0.f; }
#pragma unroll
        for (int ks = 0; ks < 2; ks++) {
            short8 bb = We2p[(w * 2 + ks) * 64 + l];
#pragma unroll
            for (int jt = 0; jt < 4; jt++) {
                short8 aa = A8[(ks * 4 + lg) * 64 + jt * 16 + lr];
                acc[jt] = __builtin_amdgcn_mfma_f32_16x16x32_bf16(aa, bb, acc[jt], 0, 0, 0);
            }
        }
        float be2 = b_e2[w * 16 + lr];
        int f = w * 16 + lr;
#pragma unroll
        for (int jt = 0; jt < 4; jt++)
#pragma unroll
            for (int r = 0; r < 4; r++) {
                int j = jt * 16 + lg * 4 + r;
                s_he[j * 66 + f] = f2bfs(acc[jt][r] + be2);
            }
        __syncthreads();
    }

    // ---------- P4: sem/euc softmax over j ----------
    {
        int hh = w, j = l;
        float acc = b_sem[hh];
        const unsigned* hp = (const unsigned*)(s_he + j * 66);
#pragma unroll 8
        for (int q = 0; q < 32; q++) {
            unsigned u = hp[q];
            acc += bflo(u) * s_wsem[(2 * q) * 4 + hh] + bfhi(u) * s_wsem[(2 * q + 1) * 4 + hh];
        }
        float cel = fmaxf(acc, 0.f) + fminf(0.f, 2.f * (__expf(0.5f * acc) - 1.f));
        float diag = (j == i) ? 1e5f : 0.f;
        float slog = cel - diag;
        float m1 = wave_max(slog);
        float e1v = __expf(slog - m1);
        float sem = e1v / wave_sum(e1v);
        float gam = __expf(log_gamma[hh]);
        float elog = -(s_xhat[j * 4 + 3] + diag) * gam;
        float m2 = wave_max(elog);
        float e2 = __expf(elog - m2);
        float euc = e2 / wave_sum(e2);
        float a = sem * euc;
        a = a / wave_sum(a);
        s_att[j * 4 + hh] = a;
    }
    __syncthreads();

    // ---------- P5: h_agg -> global (c == t) ----------
    {
        int f = t >> 2, hh = t & 3;
        float acc = 0.f;
#pragma unroll 8
        for (int j = 0; j < 64; j++) acc += bf1((ushort)s_he[j * 66 + f]) * s_att[j * 4 + hh];
        hagg_g[bi * 256 + t] = acc;
    }

    // ---------- P6: xmix GEMM in two K-halves; A region reused ----------
    f32x4 acc[4][4];
#pragma unroll
    for (int jt = 0; jt < 4; jt++)
#pragma unroll
        for (int nt = 0; nt < 4; nt++) { acc[jt][nt][0] = 0.f; acc[jt][nt][1] = 0.f; acc[jt][nt][2] = 0.f; acc[jt][nt][3] = 0.f; }

    for (int half = 0; half < 2; half++) {
        {   // build hea slots 0..15 for k in [128*half, +128)
            int j = t & 63, kc = t >> 6;
            float a0 = s_att[j * 4 + 0], a1 = s_att[j * 4 + 1];
            float a2 = s_att[j * 4 + 2], a3 = s_att[j * 4 + 3];
#pragma unroll
            for (int s = 0; s < 4; s++) {
                int sl = kc * 4 + s;
                int kbase = half * 128 + sl * 8;
                unsigned u = *(const unsigned*)(s_he + j * 66 + (kbase >> 2));
                float h0 = bflo(u), h1 = bfhi(u);
                short8 val;
                val[0] = f2bfs(h0 * a0); val[1] = f2bfs(h0 * a1);
                val[2] = f2bfs(h0 * a2); val[3] = f2bfs(h0 * a3);
                val[4] = f2bfs(h1 * a0); val[5] = f2bfs(h1 * a1);
                val[6] = f2bfs(h1 * a2); val[7] = f2bfs(h1 * a3);
                A8w[sl * 64 + j] = val;
            }
        }
        __syncthreads();
#pragma unroll
        for (int ks = 0; ks < 4; ks++) {
            short8 aa[4], bb[4];
#pragma unroll
            for (int jt = 0; jt < 4; jt++) aa[jt] = A8[(ks * 4 + lg) * 64 + jt * 16 + lr];
#pragma unroll
            for (int nt = 0; nt < 4; nt++) bb[nt] = Wxp[((w * 4 + nt) * 8 + half * 4 + ks) * 64 + l];
#pragma unroll
            for (int jt = 0; jt < 4; jt++)
#pragma unroll
                for (int nt = 0; nt < 4; nt++)
                    acc[jt][nt] = __builtin_amdgcn_mfma_f32_16x16x32_bf16(aa[jt], bb[nt], acc[jt][nt], 0, 0, 0);
        }
        __syncthreads();
    }

    // epilogue: tanh, weight by x_hat, reduce over j -> comb (mean), direct to global
    {
#pragma unroll
        for (int nt = 0; nt < 4; nt++) {
            float p0 = 0.f, p1 = 0.f, p2 = 0.f;
#pragma unroll
            for (int jt = 0; jt < 4; jt++)
#pragma unroll
                for (int r = 0; r < 4; r++) {
                    int j = jt * 16 + lg * 4 + r;
                    float th = tanhfast(acc[jt][nt][r]);
                    p0 += s_xhat[j * 4 + 0] * th;
                    p1 += s_xhat[j * 4 + 1] * th;
                    p2 += s_xhat[j * 4 + 2] * th;
                }
            p0 += __shfl_xor(p0, 16); p0 += __shfl_xor(p0, 32);
            p1 += __shfl_xor(p1, 16); p1 += __shfl_xor(p1, 32);
            p2 += __shfl_xor(p2, 16); p2 += __shfl_xor(p2, 32);
            if (lg == 0) {
                int c = w * 64 + nt * 16 + lr;
                float* cg = comb_g + bi * 768 + c * 3;
                cg[0] = p0 * (1.f / 64.f);
                cg[1] = p1 * (1.f / 64.f);
                cg[2] = p2 * (1.f / 64.f);
            }
        }
    }
}

// =============== tail: r4 verbatim — 64 blocks x 16-node tiles, MFMA MLP chain ===============
__global__ __launch_bounds__(256)
void sake_tail_kernel(
    const float* __restrict__ h, const float* __restrict__ x, const float* __restrict__ v,
    const float* __restrict__ hagg_g, const float* __restrict__ comb_g,
    const float* __restrict__ b_post1, const float* __restrict__ b_post2,
    const float* __restrict__ b_node1, const float* __restrict__ b_node2,
    const float* __restrict__ b_vel1,
    const float* __restrict__ W_vel2, const float* __restrict__ W_vmix,
    const short* __restrict__ wpack,
    float* __restrict__ out_h, float* __restrict__ out_x, float* __restrict__ out_v)
{
    const int g0 = blockIdx.x * 16;            // first node of tile
    const int t = threadIdx.x;
    const int w = t >> 6, l = t & 63, lr = l & 15, lg = l >> 4;

    // A slots: 0..31 hcp | 32..79 node1 [h|hagg|hcomb] | 80..87 post2 | 0..7 node2 | 8..15 vel1
    __shared__ __align__(16) short s_Aa[88 * 16 * 8];   // 22 KiB
    __shared__ float s_wv[256];
    __shared__ float s_wv2[64];
    __shared__ float s_red[4][16];

    const short8* A8  = (const short8*)s_Aa;
    const short8* PO1p = (const short8*)(wpack + WS_PO1);
    const short8* NO1p = (const short8*)(wpack + WS_NO1);
    const short8* PO2p = (const short8*)(wpack + WS_PO2);
    const short8* NO2p = (const short8*)(wpack + WS_NO2);
    const short8* VE1p = (const short8*)(wpack + WS_VE1);

    // ---- ph1: stage hcp (slots 0..31), h (32..39), hagg (40..71), W_vmix, W_vel2 ----
    {
        s_wv[t] = W_vmix[t];
        if (t < 64) s_wv2[t] = W_vel2[t];
        int n = t & 15, c0 = (t >> 4) * 16;
        const float* cg = comb_g + (g0 + n) * 768;
        const float* ha = hagg_g + (g0 + n) * 256;
#pragma unroll
        for (int cc = 0; cc < 16; cc++) {
            int c = c0 + cc;
            float v0 = cg[c * 3 + 0], v1 = cg[c * 3 + 1], v2 = cg[c * 3 + 2];
            float hcp = v0 * v0 + v1 * v1 + v2 * v2;
            s_Aa[((c >> 3) * 16 + n) * 8 + (c & 7)] = f2bfs(hcp);
            s_Aa[((40 + (c >> 3)) * 16 + n) * 8 + (c & 7)] = f2bfs(ha[c]);
        }
        int f0 = (t >> 4) * 4;
#pragma unroll
        for (int ff = 0; ff < 4; ff++) {
            int f = f0 + ff;
            s_Aa[((32 + (f >> 3)) * 16 + n) * 8 + (f & 7)] = f2bfs(h[(g0 + n) * 64 + f]);
        }
    }
    __syncthreads();

    // ---- ph2: post1 (K=256) -> silu -> post2-A slots 80..87 ----
    {
        f32x4 acc = {0.f, 0.f, 0.f, 0.f};
#pragma unroll
        for (int ks = 0; ks < 8; ks++) {
            short8 aa = A8[(ks * 4 + lg) * 16 + lr];
            short8 bb = PO1p[((w * 8 + ks) * 4 + lg) * 16 + lr];
            acc = __builtin_amdgcn_mfma_f32_16x16x32_bf16(aa, bb, acc, 0, 0, 0);
        }
        int f = w * 16 + lr;
        float bp = b_post1[f];
        __syncthreads();
#pragma unroll
        for (int r = 0; r < 4; r++) {
            int n = lg * 4 + r;
            s_Aa[((80 + (f >> 3)) * 16 + n) * 8 + (f & 7)] = f2bfs(siluf(acc[r] + bp));
        }
        __syncthreads();
    }

    // ---- ph3: post2 (K=64) -> silu -> hcomb slots 72..79 ----
    {
        f32x4 acc = {0.f, 0.f, 0.f, 0.f};
#pragma unroll
        for (int ks = 0; ks < 2; ks++) {
            short8 aa = A8[((80 + ks * 4 + lg)) * 16 + lr];
            short8 bb = PO2p[((w * 2 + ks) * 4 + lg) * 16 + lr];
            acc = __builtin_amdgcn_mfma_f32_16x16x32_bf16(aa, bb, acc, 0, 0, 0);
        }
        int f = w * 16 + lr;
        float bp = b_post2[f];
#pragma unroll
        for (int r = 0; r < 4; r++) {
            int n = lg * 4 + r;
            s_Aa[((72 + (f >> 3)) * 16 + n) * 8 + (f & 7)] = f2bfs(siluf(acc[r] + bp));
        }
        __syncthreads();
    }

    // ---- ph4: node1 (K=384, slots 32..79) -> silu -> node2-A slots 0..7 ----
    {
        f32x4 acc = {0.f, 0.f, 0.f, 0.f};
#pragma unroll
        for (int ks = 0; ks < 12; ks++) {
            short8 aa = A8[((32 + ks * 4 + lg)) * 16 + lr];
            short8 bb = NO1p[((w * 12 + ks) * 4 + lg) * 16 + lr];
            acc = __builtin_amdgcn_mfma_f32_16x16x32_bf16(aa, bb, acc, 0, 0, 0);
        }
        int f = w * 16 + lr;
        float bp = b_node1[f];
#pragma unroll
        for (int r = 0; r < 4; r++) {
            int n = lg * 4 + r;
            s_Aa[((f >> 3) * 16 + n) * 8 + (f & 7)] = f2bfs(siluf(acc[r] + bp));
        }
        __syncthreads();
    }

    // ---- ph5: node2 (K=64) + residual -> out_h, vel1-A slots 8..15 ----
    {
        f32x4 acc = {0.f, 0.f, 0.f, 0.f};
#pragma unroll
        for (int ks = 0; ks < 2; ks++) {
            short8 aa = A8[(ks * 4 + lg) * 16 + lr];
            short8 bb = NO2p[((w * 2 + ks) * 4 + lg) * 16 + lr];
            acc = __builtin_amdgcn_mfma_f32_16x16x32_bf16(aa, bb, acc, 0, 0, 0);
        }
        int f = w * 16 + lr;
        float bp = b_node2[f];
#pragma unroll
        for (int r = 0; r < 4; r++) {
            int n = lg * 4 + r;
            float ho = h[(g0 + n) * 64 + f] + siluf(acc[r] + bp);
            out_h[(g0 + n) * 64 + f] = ho;
            s_Aa[((8 + (f >> 3)) * 16 + n) * 8 + (f & 7)] = f2bfs(ho);
        }
        __syncthreads();
    }

    // ---- ph6: vel1 (K=64) -> silu -> gate partials ----
    {
        f32x4 acc = {0.f, 0.f, 0.f, 0.f};
#pragma unroll
        for (int ks = 0; ks < 2; ks++) {
            short8 aa = A8[((8 + ks * 4 + lg)) * 16 + lr];
            short8 bb = VE1p[((w * 2 + ks) * 4 + lg) * 16 + lr];
            acc = __builtin_amdgcn_mfma_f32_16x16x32_bf16(aa, bb, acc, 0, 0, 0);
        }
        int f = w * 16 + lr;
        float bp = b_vel1[f];
        float wv2 = s_wv2[f];
#pragma unroll
        for (int r = 0; r < 4; r++) {
            float p = siluf(acc[r] + bp) * wv2;
            p += __shfl_xor(p, 1); p += __shfl_xor(p, 2);
            p += __shfl_xor(p, 4); p += __shfl_xor(p, 8);
            if (lr == 0) s_red[w][lg * 4 + r] = p;   // partial over this wave's 16 f
        }
        __syncthreads();
    }

    // ---- ph7: gate + delta_v + v/x outputs ----
    {
        int n = t >> 4, q = t & 15;
        float p0 = 0.f, p1 = 0.f, p2 = 0.f;
        const float* cg = comb_g + (g0 + n) * 768;
#pragma unroll
        for (int cc = 0; cc < 16; cc++) {
            int c = q * 16 + cc;
            float wv = s_wv[c];
            p0 += cg[c * 3 + 0] * wv;
            p1 += cg[c * 3 + 1] * wv;
            p2 += cg[c * 3 + 2] * wv;
        }
        p0 += __shfl_xor(p0, 1); p0 += __shfl_xor(p0, 2); p0 += __shfl_xor(p0, 4); p0 += __shfl_xor(p0, 8);
        p1 += __shfl_xor(p1, 1); p1 += __shfl_xor(p1, 2); p1 += __shfl_xor(p1, 4); p1 += __shfl_xor(p1, 8);
        p2 += __shfl_xor(p2, 1); p2 += __shfl_xor(p2, 2); p2 += __shfl_xor(p2, 4); p2 += __shfl_xor(p2, 8);
        if (q == 0) {
            float g = s_red[0][n] + s_red[1][n] + s_red[2][n] + s_red[3][n];
            g = 2.f / (1.f + __expf(-g));
            float dv0 = p0 + g * v[(g0 + n) * 3 + 0];
            float dv1 = p1 + g * v[(g0 + n) * 3 + 1];
            float dv2 = p2 + g * v[(g0 + n) * 3 + 2];
            out_v[(g0 + n) * 3 + 0] = dv0;
            out_v[(g0 + n) * 3 + 1] = dv1;
            out_v[(g0 + n) * 3 + 2] = dv2;
            out_x[(g0 + n) * 3 + 0] = x[(g0 + n) * 3 + 0] + dv0;
            out_x[(g0 + n) * 3 + 1] = x[(g0 + n) * 3 + 1] + dv1;
            out_x[(g0 + n) * 3 + 2] = x[(g0 + n) * 3 + 2] + dv2;
        }
    }
}

extern "C" void kernel_launch(void* const* d_in, const int* in_sizes, int n_in,
                              void* d_out, int out_size, void* d_ws, size_t ws_size,
                              hipStream_t stream) {
    const float* h        = (const float*)d_in[0];
    const float* x        = (const float*)d_in[1];
    const float* v        = (const float*)d_in[2];
    const float* W_in     = (const float*)d_in[3];
    const float* b_in     = (const float*)d_in[4];
    const float* rbf_m    = (const float*)d_in[5];
    const float* rbf_b    = (const float*)d_in[6];
    const float* W_e1     = (const float*)d_in[7];
    const float* b_e1     = (const float*)d_in[8];
    const float* W_e2     = (const float*)d_in[9];
    const float* b_e2     = (const float*)d_in[10];
    const float* W_sem    = (const float*)d_in[11];
    const float* b_sem    = (const float*)d_in[12];
    const float* log_g    = (const float*)d_in[13];
    const float* W_xmix   = (const float*)d_in[14];
    const float* W_post1  = (const float*)d_in[15];
    const float* b_post1  = (const float*)d_in[16];
    const float* W_post2  = (const float*)d_in[17];
    const float* b_post2  = (const float*)d_in[18];
    const float* W_node1  = (const float*)d_in[19];
    const float* b_node1  = (const float*)d_in[20];
    const float* W_node2  = (const float*)d_in[21];
    const float* b_node2  = (const float*)d_in[22];
    const float* W_vel1   = (const float*)d_in[23];
    const float* b_vel1   = (const float*)d_in[24];
    const float* W_vel2   = (const float*)d_in[25];
    const float* W_vmix   = (const float*)d_in[26];

    float* out   = (float*)d_out;
    float* out_h = out;
    float* out_x = out + NB * NN * NF;
    float* out_v = out + NB * NN * NF + NB * NN * 3;

    short* wpack = (short*)d_ws;
    float* wsf   = (float*)d_ws;
    float* mid   = wsf + MID_F;
    float* e1    = wsf + E1_F;
    float* hagg  = wsf + HAGG_F;
    float* comb  = wsf + COMB_F;

    prep_kernel<<<62 + 256, 256, 0, stream>>>(
        W_e1, b_e1, W_e2, W_xmix, W_post1, W_node1, W_post2, W_node2, W_vel1,
        h, W_in, b_in, wpack, mid, e1);

    sake_edge_kernel<<<NB * NN, 256, 0, stream>>>(
        x, mid, e1, rbf_m, rbf_b, b_e1, b_e2, W_sem, b_sem, log_g,
        wpack, hagg, comb);

    sake_tail_kernel<<<64, 256, 0, stream>>>(
        h, x, v, hagg, comb,
        b_post1, b_post2, b_node1, b_node2, b_vel1,
        W_vel2, W_vmix, wpack, out_h, out_x, out_v);
}